// Round 1
// baseline (492.936 us; speedup 1.0000x reference)
//
#include <hip/hip_runtime.h>
#include <hip/hip_bf16.h>
#include <cstdint>

#define B_SZ 16
#define C_IN 512
#define C8   64
#define NSP  4096   // H*W
#define QR   192    // q,k,v stacked rows

// ---------------------------------------------------------------------------
// K1: qkv[b, o, n] = W{q,k,v}[o,:] . x[b,:,n] + b{q,k,v}[o]
// grid (NSP/64, B), block 256. Block computes all 192 rows x 64 cols.
// Thread tile: 12 rows x 4 cols (48 acc). K staged in chunks of 32.
// LDS: xs[32][68] (+pad, b128-aligned), wsT[32][196] transposed W.
// ---------------------------------------------------------------------------
__global__ __launch_bounds__(256) void k_qkv(
    const float* __restrict__ x,
    const float* __restrict__ Wq, const float* __restrict__ bq,
    const float* __restrict__ Wk, const float* __restrict__ bk,
    const float* __restrict__ Wv, const float* __restrict__ bv,
    float* __restrict__ qkv)
{
    __shared__ float xs[32][68];
    __shared__ float wsT[32][196];
    const int b  = blockIdx.y;
    const int n0 = blockIdx.x * 64;
    const int t  = threadIdx.x;
    const int tx = t & 15;   // col group (4 cols)
    const int ty = t >> 4;   // row group (12 rows)

    float acc[12][4];
#pragma unroll
    for (int r = 0; r < 12; ++r)
#pragma unroll
        for (int j = 0; j < 4; ++j) acc[r][j] = 0.f;

    const float* xb = x + (size_t)b * C_IN * NSP + n0;

    for (int k0 = 0; k0 < C_IN; k0 += 32) {
        // stage x tile: 32 k-rows x 64 cols = 512 float4, 2 per thread
#pragma unroll
        for (int i = 0; i < 2; ++i) {
            int idx = t + 256 * i;
            int r = idx >> 4, c4 = idx & 15;
            float4 v = *reinterpret_cast<const float4*>(
                xb + (size_t)(k0 + r) * NSP + c4 * 4);
            *reinterpret_cast<float4*>(&xs[r][c4 * 4]) = v;
        }
        // stage W transposed: 192 rows x 32 k = 1536 float4, 6 per thread
#pragma unroll
        for (int i = 0; i < 6; ++i) {
            int idx = t + 256 * i;    // 0..1535
            int o  = idx >> 3;        // 8 float4 per row-chunk of 32 k
            int k4 = idx & 7;
            const float* wrow;
            if (o < 64)       wrow = Wq + (size_t)o * C_IN;
            else if (o < 128) wrow = Wk + (size_t)(o - 64) * C_IN;
            else              wrow = Wv + (size_t)(o - 128) * C_IN;
            float4 w = *reinterpret_cast<const float4*>(wrow + k0 + k4 * 4);
            wsT[k4 * 4 + 0][o] = w.x;
            wsT[k4 * 4 + 1][o] = w.y;
            wsT[k4 * 4 + 2][o] = w.z;
            wsT[k4 * 4 + 3][o] = w.w;
        }
        __syncthreads();
#pragma unroll 8
        for (int kk = 0; kk < 32; ++kk) {
            float4 xv = *reinterpret_cast<const float4*>(&xs[kk][tx * 4]);
            float4 w0 = *reinterpret_cast<const float4*>(&wsT[kk][ty * 12]);
            float4 w1 = *reinterpret_cast<const float4*>(&wsT[kk][ty * 12 + 4]);
            float4 w2 = *reinterpret_cast<const float4*>(&wsT[kk][ty * 12 + 8]);
            const float xr[4] = {xv.x, xv.y, xv.z, xv.w};
            const float wr[12] = {w0.x, w0.y, w0.z, w0.w,
                                  w1.x, w1.y, w1.z, w1.w,
                                  w2.x, w2.y, w2.z, w2.w};
#pragma unroll
            for (int r = 0; r < 12; ++r)
#pragma unroll
                for (int j = 0; j < 4; ++j)
                    acc[r][j] = fmaf(wr[r], xr[j], acc[r][j]);
        }
        __syncthreads();
    }
    // epilogue: bias + store (float4, coalesced within 16-lane groups)
#pragma unroll
    for (int r = 0; r < 12; ++r) {
        int o = ty * 12 + r;
        float bias = (o < 64) ? bq[o] : (o < 128) ? bk[o - 64] : bv[o - 128];
        float4 ov;
        ov.x = acc[r][0] + bias; ov.y = acc[r][1] + bias;
        ov.z = acc[r][2] + bias; ov.w = acc[r][3] + bias;
        *reinterpret_cast<float4*>(
            qkv + ((size_t)b * QR + o) * NSP + n0 + tx * 4) = ov;
    }
}

// ---------------------------------------------------------------------------
// K2a: partial energy[b, s, c, d] = sum_{n in chunk s} q[b,c,n]*k[b,d,n]
// grid (32, B), block 256, n-chunk = 128. Thread tile 4x4 (c x d).
// qs/ks stride 133: read conflicts <= 2-way (533*4*cg % 32 pattern).
// ---------------------------------------------------------------------------
__global__ __launch_bounds__(256) void k_energy(
    const float* __restrict__ qkv, float* __restrict__ part)
{
    __shared__ float qs[64][133];
    __shared__ float ks[64][133];
    const int b = blockIdx.y, s = blockIdx.x;
    const int n0 = s * 128;
    const int t = threadIdx.x;
    const int cg = t & 15, dg = t >> 4;
    const float* qb = qkv + (size_t)b * QR * NSP + n0;
    const float* kb = qb + (size_t)C8 * NSP;
#pragma unroll
    for (int i = 0; i < 8; ++i) {
        int idx = t + 256 * i;      // 0..2047 float4
        int c = idx >> 5, j4 = idx & 31;
        float4 qv = *reinterpret_cast<const float4*>(qb + (size_t)c * NSP + j4 * 4);
        float4 kv = *reinterpret_cast<const float4*>(kb + (size_t)c * NSP + j4 * 4);
        qs[c][j4 * 4 + 0] = qv.x; qs[c][j4 * 4 + 1] = qv.y;
        qs[c][j4 * 4 + 2] = qv.z; qs[c][j4 * 4 + 3] = qv.w;
        ks[c][j4 * 4 + 0] = kv.x; ks[c][j4 * 4 + 1] = kv.y;
        ks[c][j4 * 4 + 2] = kv.z; ks[c][j4 * 4 + 3] = kv.w;
    }
    __syncthreads();
    float acc[4][4];
#pragma unroll
    for (int i = 0; i < 4; ++i)
#pragma unroll
        for (int j = 0; j < 4; ++j) acc[i][j] = 0.f;

#pragma unroll 4
    for (int nn = 0; nn < 128; ++nn) {
        float qv[4], kv[4];
#pragma unroll
        for (int i = 0; i < 4; ++i) qv[i] = qs[cg * 4 + i][nn];
#pragma unroll
        for (int j = 0; j < 4; ++j) kv[j] = ks[dg * 4 + j][nn];
#pragma unroll
        for (int i = 0; i < 4; ++i)
#pragma unroll
            for (int j = 0; j < 4; ++j)
                acc[i][j] = fmaf(qv[i], kv[j], acc[i][j]);
    }
#pragma unroll
    for (int i = 0; i < 4; ++i) {
        float4 ov;
        ov.x = acc[i][0]; ov.y = acc[i][1]; ov.z = acc[i][2]; ov.w = acc[i][3];
        *reinterpret_cast<float4*>(
            part + (((size_t)b * 32 + s) * 64 + cg * 4 + i) * 64 + dg * 4) = ov;
    }
}

// ---------------------------------------------------------------------------
// K2b: reduce 32 partials -> energy, rowwise softmax -> attn[b, c, d]
// grid (B), block 256.
// ---------------------------------------------------------------------------
__global__ __launch_bounds__(256) void k_softmax(
    const float* __restrict__ part, float* __restrict__ attn)
{
    __shared__ float es[64][65];
    const int b = blockIdx.x, t = threadIdx.x;
#pragma unroll 4
    for (int i = 0; i < 16; ++i) {
        int idx = t + 256 * i;   // 0..4095
        float sum = 0.f;
        for (int s = 0; s < 32; ++s)
            sum += part[((size_t)b * 32 + s) * 4096 + idx];
        es[idx >> 6][idx & 63] = sum;
    }
    __syncthreads();
    if (t < 64) {
        float m = -1e30f;
#pragma unroll 8
        for (int d = 0; d < 64; ++d) m = fmaxf(m, es[t][d]);
        float sum = 0.f;
#pragma unroll 8
        for (int d = 0; d < 64; ++d) {
            float e = expf(es[t][d] - m);
            es[t][d] = e;
            sum += e;
        }
        float rn = 1.f / sum;
#pragma unroll 8
        for (int d = 0; d < 64; ++d)
            attn[((size_t)b * 64 + t) * 64 + d] = es[t][d] * rn;
    }
}

// ---------------------------------------------------------------------------
// K2c: M[b, o, d] = sum_c Wo[o, c] * attn[b, c, d]   (fused Wo @ attn)
// grid (8, B), block 256, 64 o-rows per block, K = 64.
// ---------------------------------------------------------------------------
__global__ __launch_bounds__(256) void k_woattn(
    const float* __restrict__ Wo, const float* __restrict__ attn,
    float* __restrict__ Mmat)
{
    __shared__ float wosT[64][68];  // [c][o_local]
    __shared__ float as[64][68];    // [c][d]
    const int b  = blockIdx.y;
    const int o0 = blockIdx.x * 64;
    const int t  = threadIdx.x;
    const int td = t & 15, to = t >> 4;
#pragma unroll
    for (int i = 0; i < 4; ++i) {
        int idx = t + 256 * i;    // 0..1023
        int r = idx >> 4, q4 = idx & 15;
        float4 w = *reinterpret_cast<const float4*>(
            Wo + (size_t)(o0 + r) * 64 + q4 * 4);
        wosT[q4 * 4 + 0][r] = w.x; wosT[q4 * 4 + 1][r] = w.y;
        wosT[q4 * 4 + 2][r] = w.z; wosT[q4 * 4 + 3][r] = w.w;
        float4 a = *reinterpret_cast<const float4*>(
            attn + ((size_t)b * 64 + r) * 64 + q4 * 4);
        *reinterpret_cast<float4*>(&as[r][q4 * 4]) = a;
    }
    __syncthreads();
    float acc[4][4];
#pragma unroll
    for (int i = 0; i < 4; ++i)
#pragma unroll
        for (int j = 0; j < 4; ++j) acc[i][j] = 0.f;
#pragma unroll 8
    for (int kk = 0; kk < 64; ++kk) {
        float4 wv = *reinterpret_cast<const float4*>(&wosT[kk][to * 4]);
        float4 av = *reinterpret_cast<const float4*>(&as[kk][td * 4]);
        const float wr[4] = {wv.x, wv.y, wv.z, wv.w};
        const float ar[4] = {av.x, av.y, av.z, av.w};
#pragma unroll
        for (int i = 0; i < 4; ++i)
#pragma unroll
            for (int j = 0; j < 4; ++j)
                acc[i][j] = fmaf(wr[i], ar[j], acc[i][j]);
    }
#pragma unroll
    for (int i = 0; i < 4; ++i) {
        float4 ov;
        ov.x = acc[i][0]; ov.y = acc[i][1]; ov.z = acc[i][2]; ov.w = acc[i][3];
        *reinterpret_cast<float4*>(
            Mmat + ((size_t)b * 512 + o0 + to * 4 + i) * 64 + td * 4) = ov;
    }
}

// ---------------------------------------------------------------------------
// K3: out[b, o, n] = sum_d M[b, o, d] * v[b, d, n] + bo[o]
// grid (64, 8, B), block 256, 64x64 tile, K = 64 (single chunk).
// ---------------------------------------------------------------------------
__global__ __launch_bounds__(256) void k_out(
    const float* __restrict__ qkv, const float* __restrict__ Mmat,
    const float* __restrict__ bo, float* __restrict__ out)
{
    __shared__ float vs[64][68];    // [d][n]
    __shared__ float msT[64][68];   // [d][o_local]
    const int b  = blockIdx.z;
    const int o0 = blockIdx.y * 64;
    const int n0 = blockIdx.x * 64;
    const int t  = threadIdx.x;
    const int tn = t & 15, to = t >> 4;
    const float* vb = qkv + ((size_t)b * QR + 128) * NSP + n0;
#pragma unroll
    for (int i = 0; i < 4; ++i) {
        int idx = t + 256 * i;
        int r = idx >> 4, q4 = idx & 15;
        float4 v = *reinterpret_cast<const float4*>(vb + (size_t)r * NSP + q4 * 4);
        *reinterpret_cast<float4*>(&vs[r][q4 * 4]) = v;
        float4 m = *reinterpret_cast<const float4*>(
            Mmat + ((size_t)b * 512 + o0 + r) * 64 + q4 * 4);
        msT[q4 * 4 + 0][r] = m.x; msT[q4 * 4 + 1][r] = m.y;
        msT[q4 * 4 + 2][r] = m.z; msT[q4 * 4 + 3][r] = m.w;
    }
    __syncthreads();
    float acc[4][4];
#pragma unroll
    for (int i = 0; i < 4; ++i)
#pragma unroll
        for (int j = 0; j < 4; ++j) acc[i][j] = 0.f;
#pragma unroll 8
    for (int kk = 0; kk < 64; ++kk) {
        float4 mv = *reinterpret_cast<const float4*>(&msT[kk][to * 4]);
        float4 vv = *reinterpret_cast<const float4*>(&vs[kk][tn * 4]);
        const float mr[4] = {mv.x, mv.y, mv.z, mv.w};
        const float vr[4] = {vv.x, vv.y, vv.z, vv.w};
#pragma unroll
        for (int i = 0; i < 4; ++i)
#pragma unroll
            for (int j = 0; j < 4; ++j)
                acc[i][j] = fmaf(mr[i], vr[j], acc[i][j]);
    }
#pragma unroll
    for (int i = 0; i < 4; ++i) {
        int o = o0 + to * 4 + i;
        float bias = bo[o];
        float4 ov;
        ov.x = acc[i][0] + bias; ov.y = acc[i][1] + bias;
        ov.z = acc[i][2] + bias; ov.w = acc[i][3] + bias;
        *reinterpret_cast<float4*>(
            out + ((size_t)b * 512 + o) * NSP + n0 + tn * 4) = ov;
    }
}

// ---------------------------------------------------------------------------
extern "C" void kernel_launch(void* const* d_in, const int* in_sizes, int n_in,
                              void* d_out, int out_size, void* d_ws, size_t ws_size,
                              hipStream_t stream)
{
    const float* x  = (const float*)d_in[0];
    const float* Wq = (const float*)d_in[1];
    const float* bq = (const float*)d_in[2];
    const float* Wk = (const float*)d_in[3];
    const float* bk = (const float*)d_in[4];
    const float* Wv = (const float*)d_in[5];
    const float* bv = (const float*)d_in[6];
    const float* Wo = (const float*)d_in[7];
    const float* bo = (const float*)d_in[8];
    float* out = (float*)d_out;

    float* ws   = (float*)d_ws;
    float* qkv  = ws;                                   // [B,192,N]   48 MiB
    float* part = qkv  + (size_t)B_SZ * QR * NSP;       // [B,32,64,64] 8 MiB
    float* attn = part + (size_t)B_SZ * 32 * 64 * 64;   // [B,64,64]  256 KiB
    float* Mmat = attn + (size_t)B_SZ * 64 * 64;        // [B,512,64]   2 MiB

    k_qkv   <<<dim3(64, B_SZ),    256, 0, stream>>>(x, Wq, bq, Wk, bk, Wv, bv, qkv);
    k_energy<<<dim3(32, B_SZ),    256, 0, stream>>>(qkv, part);
    k_softmax<<<dim3(B_SZ),       256, 0, stream>>>(part, attn);
    k_woattn<<<dim3(8, B_SZ),     256, 0, stream>>>(Wo, attn, Mmat);
    k_out   <<<dim3(64, 8, B_SZ), 256, 0, stream>>>(qkv, Mmat, bo, out);
}

// Round 2
// 333.575 us; speedup vs baseline: 1.4777x; 1.4777x over previous
//
#include <hip/hip_runtime.h>
#include <hip/hip_bf16.h>
#include <cstdint>

#define B_SZ 16
#define C_IN 512
#define C8   64
#define NSP  4096   // H*W
#define QR   192    // q,k,v stacked rows

typedef __attribute__((ext_vector_type(8))) short s8v;   // 8 bf16 (4 VGPRs)
typedef __attribute__((ext_vector_type(4))) float f4v;   // MFMA acc

// split fp32 -> truncated bf16 hi + bf16(residual). |x - hi - lo| <= ~2^-16 |x|
__device__ __forceinline__ void split_bf16(float x, unsigned short& h, unsigned short& l) {
    unsigned int u = __float_as_uint(x);
    h = (unsigned short)(u >> 16);
    float r = x - __uint_as_float(u & 0xffff0000u);
    l = (unsigned short)(__float_as_uint(r) >> 16);
}

// ---------------------------------------------------------------------------
// W pre-convert: stacked [192][512] -> whi/wlo bf16 (stored as ushort).
// Runs every call (ws is re-poisoned by the harness).
// ---------------------------------------------------------------------------
__global__ __launch_bounds__(256) void k_convW(
    const float* __restrict__ Wq, const float* __restrict__ Wk,
    const float* __restrict__ Wv,
    unsigned short* __restrict__ whi, unsigned short* __restrict__ wlo)
{
    const int o = blockIdx.x;
    const float* src = (o < 64)  ? (Wq + (size_t)o * C_IN)
                     : (o < 128) ? (Wk + (size_t)(o - 64) * C_IN)
                                 : (Wv + (size_t)(o - 128) * C_IN);
    for (int c = threadIdx.x; c < C_IN; c += 256) {
        unsigned short h, l;
        split_bf16(src[c], h, l);
        whi[(size_t)o * C_IN + c] = h;
        wlo[(size_t)o * C_IN + c] = l;
    }
}

// ---------------------------------------------------------------------------
// K1: qkv = W.x via split-bf16 MFMA. grid (32, B), 512 thr = 8 waves (4M x 2N).
// Block tile 192x128, BK=32. LDS 40 KB, 2 blocks/CU.
// A frag: m = lane&15, k = 8*(lane>>4)+j (k-contiguous LDS, XOR slot swizzle).
// C frag: col = lane&15, row = (lane>>4)*4 + reg  [m89-verified].
// acc = Ah*Bh + Ah*Bl + Al*Bh  (drop lo*lo; error ~2^-15 rel).
// ---------------------------------------------------------------------------
__global__ __launch_bounds__(512, 4) void k_qkv_mfma(
    const float* __restrict__ x,
    const unsigned short* __restrict__ whi, const unsigned short* __restrict__ wlo,
    const float* __restrict__ bq, const float* __restrict__ bk,
    const float* __restrict__ bv,
    float* __restrict__ qkv)
{
    __shared__ unsigned short as_h[QR * 32], as_l[QR * 32];     // 12 KB each
    __shared__ unsigned short xs_h[128 * 32], xs_l[128 * 32];   //  8 KB each

    const int b  = blockIdx.y;
    const int n0 = blockIdx.x * 128;
    const int t  = threadIdx.x;
    const int w  = t >> 6;
    const int l  = t & 63;
    const int wm = w >> 1;                 // 0..3 -> m base wm*48
    const int wn = w & 1;                  // 0..1 -> n base wn*64
    const int lm = l & 15;
    const int slot = (((l >> 4) ^ (l & 3)) << 3);  // ushort offset in 32-wide row

    // B staging mapping: thread -> (n within tile, k-group)
    const int nB    = t & 127;
    const int kgB   = t >> 7;              // 0..3
    const int slotB = ((kgB ^ (nB & 3)) << 3);

    f4v acc[3][4];
#pragma unroll
    for (int i = 0; i < 3; ++i)
#pragma unroll
        for (int j = 0; j < 4; ++j) acc[i][j] = (f4v)0.f;

    const float* xcol = x + ((size_t)b * C_IN) * NSP + n0 + nB;
    float xr[8];
    auto loadB = [&](int K0) {
        const float* s_ = xcol + (size_t)(K0 + kgB * 8) * NSP;
#pragma unroll
        for (int j = 0; j < 8; ++j) xr[j] = s_[(size_t)j * NSP];
    };
    loadB(0);

    for (int it = 0; it < 16; ++it) {
        const int k0 = it * 32;
        __syncthreads();                    // prev compute done; LDS writable
        // ---- write x tile (convert to hi/lo), one b128 each
        {
            unsigned short h[8], lo[8];
#pragma unroll
            for (int j = 0; j < 8; ++j) split_bf16(xr[j], h[j], lo[j]);
            s8v hv, lv;
#pragma unroll
            for (int j = 0; j < 8; ++j) { hv[j] = (short)h[j]; lv[j] = (short)lo[j]; }
            *(s8v*)&xs_h[nB * 32 + slotB] = hv;
            *(s8v*)&xs_l[nB * 32 + slotB] = lv;
        }
        // ---- stage W tile (pre-converted, L2-hot)
        for (int c = t; c < 768; c += 512) {
            const int m = c >> 2, kga = c & 3;
            const int dst = m * 32 + ((kga ^ (m & 3)) << 3);
            const size_t srcoff = (size_t)m * C_IN + k0 + kga * 8;
            *(s8v*)&as_h[dst] = *(const s8v*)&whi[srcoff];
            *(s8v*)&as_l[dst] = *(const s8v*)&wlo[srcoff];
        }
        // ---- prefetch next x chunk (in flight across the barrier / compute)
        if (it < 15) loadB(k0 + 32);
        __syncthreads();                    // LDS ready
        // ---- fragments + 36 MFMA
        s8v ah[3], al[3], bh[4], bl[4];
#pragma unroll
        for (int fm = 0; fm < 3; ++fm) {
            const int m = wm * 48 + fm * 16 + lm;
            ah[fm] = *(const s8v*)&as_h[m * 32 + slot];
            al[fm] = *(const s8v*)&as_l[m * 32 + slot];
        }
#pragma unroll
        for (int fn = 0; fn < 4; ++fn) {
            const int n = wn * 64 + fn * 16 + lm;
            bh[fn] = *(const s8v*)&xs_h[n * 32 + slot];
            bl[fn] = *(const s8v*)&xs_l[n * 32 + slot];
        }
#pragma unroll
        for (int fm = 0; fm < 3; ++fm)
#pragma unroll
            for (int fn = 0; fn < 4; ++fn) {
                acc[fm][fn] = __builtin_amdgcn_mfma_f32_16x16x32_bf16(
                    ah[fm], bh[fn], acc[fm][fn], 0, 0, 0);
                acc[fm][fn] = __builtin_amdgcn_mfma_f32_16x16x32_bf16(
                    ah[fm], bl[fn], acc[fm][fn], 0, 0, 0);
                acc[fm][fn] = __builtin_amdgcn_mfma_f32_16x16x32_bf16(
                    al[fm], bh[fn], acc[fm][fn], 0, 0, 0);
            }
    }

    // ---- epilogue: bias + store
#pragma unroll
    for (int fm = 0; fm < 3; ++fm) {
        const int row0 = wm * 48 + fm * 16;               // 16-aligned, never crosses 64
        const float* barr = (row0 < 64) ? bq : (row0 < 128) ? bk : bv;
        const int rbase = (row0 & 63) + (l >> 4) * 4;
        const int rowg  = row0 + (l >> 4) * 4;
#pragma unroll
        for (int fn = 0; fn < 4; ++fn) {
            const int col = n0 + wn * 64 + fn * 16 + lm;
            float* dst = qkv + ((size_t)b * QR + rowg) * NSP + col;
#pragma unroll
            for (int r = 0; r < 4; ++r)
                dst[(size_t)r * NSP] = acc[fm][fn][r] + barr[rbase + r];
        }
    }
}

// ---------------------------------------------------------------------------
// K2a: partial energy over n-chunks (unchanged, fp32 vector)
// ---------------------------------------------------------------------------
__global__ __launch_bounds__(256) void k_energy(
    const float* __restrict__ qkv, float* __restrict__ part)
{
    __shared__ float qs[64][133];
    __shared__ float ks[64][133];
    const int b = blockIdx.y, s = blockIdx.x;
    const int n0 = s * 128;
    const int t = threadIdx.x;
    const int cg = t & 15, dg = t >> 4;
    const float* qb = qkv + (size_t)b * QR * NSP + n0;
    const float* kb = qb + (size_t)C8 * NSP;
#pragma unroll
    for (int i = 0; i < 8; ++i) {
        int idx = t + 256 * i;
        int c = idx >> 5, j4 = idx & 31;
        float4 qv = *reinterpret_cast<const float4*>(qb + (size_t)c * NSP + j4 * 4);
        float4 kv = *reinterpret_cast<const float4*>(kb + (size_t)c * NSP + j4 * 4);
        qs[c][j4 * 4 + 0] = qv.x; qs[c][j4 * 4 + 1] = qv.y;
        qs[c][j4 * 4 + 2] = qv.z; qs[c][j4 * 4 + 3] = qv.w;
        ks[c][j4 * 4 + 0] = kv.x; ks[c][j4 * 4 + 1] = kv.y;
        ks[c][j4 * 4 + 2] = kv.z; ks[c][j4 * 4 + 3] = kv.w;
    }
    __syncthreads();
    float acc[4][4];
#pragma unroll
    for (int i = 0; i < 4; ++i)
#pragma unroll
        for (int j = 0; j < 4; ++j) acc[i][j] = 0.f;
#pragma unroll 4
    for (int nn = 0; nn < 128; ++nn) {
        float qv[4], kv[4];
#pragma unroll
        for (int i = 0; i < 4; ++i) qv[i] = qs[cg * 4 + i][nn];
#pragma unroll
        for (int j = 0; j < 4; ++j) kv[j] = ks[dg * 4 + j][nn];
#pragma unroll
        for (int i = 0; i < 4; ++i)
#pragma unroll
            for (int j = 0; j < 4; ++j)
                acc[i][j] = fmaf(qv[i], kv[j], acc[i][j]);
    }
#pragma unroll
    for (int i = 0; i < 4; ++i) {
        float4 ov;
        ov.x = acc[i][0]; ov.y = acc[i][1]; ov.z = acc[i][2]; ov.w = acc[i][3];
        *reinterpret_cast<float4*>(
            part + (((size_t)b * 32 + s) * 64 + cg * 4 + i) * 64 + dg * 4) = ov;
    }
}

// ---------------------------------------------------------------------------
// K2b: reduce partials + rowwise softmax. grid (64, B) — one c-row per block.
// ---------------------------------------------------------------------------
__global__ __launch_bounds__(256) void k_softmax(
    const float* __restrict__ part, float* __restrict__ attn)
{
    __shared__ float red[4][64];
    const int cRow = blockIdx.x, b = blockIdx.y;
    const int t = threadIdx.x, d = t & 63, sg = t >> 6;
    const float* p = part + (size_t)b * 32 * 4096 + cRow * 64 + d;
    float s = 0.f;
#pragma unroll
    for (int i = 0; i < 8; ++i) s += p[(size_t)(sg * 8 + i) * 4096];
    red[sg][d] = s;
    __syncthreads();
    if (t < 64) {
        float v = red[0][d] + red[1][d] + red[2][d] + red[3][d];
        float m = v;
#pragma unroll
        for (int off = 32; off; off >>= 1) m = fmaxf(m, __shfl_xor(m, off));
        float e = __expf(v - m);
        float sum = e;
#pragma unroll
        for (int off = 32; off; off >>= 1) sum += __shfl_xor(sum, off);
        attn[((size_t)b * 64 + cRow) * 64 + d] = e / sum;
    }
}

// ---------------------------------------------------------------------------
// K2c: M = Wo @ attn (unchanged)
// ---------------------------------------------------------------------------
__global__ __launch_bounds__(256) void k_woattn(
    const float* __restrict__ Wo, const float* __restrict__ attn,
    float* __restrict__ Mmat)
{
    __shared__ float wosT[64][68];
    __shared__ float as[64][68];
    const int b  = blockIdx.y;
    const int o0 = blockIdx.x * 64;
    const int t  = threadIdx.x;
    const int td = t & 15, to = t >> 4;
#pragma unroll
    for (int i = 0; i < 4; ++i) {
        int idx = t + 256 * i;
        int r = idx >> 4, q4 = idx & 15;
        float4 w = *reinterpret_cast<const float4*>(
            Wo + (size_t)(o0 + r) * 64 + q4 * 4);
        wosT[q4 * 4 + 0][r] = w.x; wosT[q4 * 4 + 1][r] = w.y;
        wosT[q4 * 4 + 2][r] = w.z; wosT[q4 * 4 + 3][r] = w.w;
        float4 a = *reinterpret_cast<const float4*>(
            attn + ((size_t)b * 64 + r) * 64 + q4 * 4);
        *reinterpret_cast<float4*>(&as[r][q4 * 4]) = a;
    }
    __syncthreads();
    float acc[4][4];
#pragma unroll
    for (int i = 0; i < 4; ++i)
#pragma unroll
        for (int j = 0; j < 4; ++j) acc[i][j] = 0.f;
#pragma unroll 8
    for (int kk = 0; kk < 64; ++kk) {
        float4 wv = *reinterpret_cast<const float4*>(&wosT[kk][to * 4]);
        float4 av = *reinterpret_cast<const float4*>(&as[kk][td * 4]);
        const float wr[4] = {wv.x, wv.y, wv.z, wv.w};
        const float ar[4] = {av.x, av.y, av.z, av.w};
#pragma unroll
        for (int i = 0; i < 4; ++i)
#pragma unroll
            for (int j = 0; j < 4; ++j)
                acc[i][j] = fmaf(wr[i], ar[j], acc[i][j]);
    }
#pragma unroll
    for (int i = 0; i < 4; ++i) {
        float4 ov;
        ov.x = acc[i][0]; ov.y = acc[i][1]; ov.z = acc[i][2]; ov.w = acc[i][3];
        *reinterpret_cast<float4*>(
            Mmat + ((size_t)b * 512 + o0 + to * 4 + i) * 64 + td * 4) = ov;
    }
}

// ---------------------------------------------------------------------------
// K3: out = M @ v + bo (unchanged)
// ---------------------------------------------------------------------------
__global__ __launch_bounds__(256) void k_out(
    const float* __restrict__ qkv, const float* __restrict__ Mmat,
    const float* __restrict__ bo, float* __restrict__ out)
{
    __shared__ float vs[64][68];
    __shared__ float msT[64][68];
    const int b  = blockIdx.z;
    const int o0 = blockIdx.y * 64;
    const int n0 = blockIdx.x * 64;
    const int t  = threadIdx.x;
    const int tn = t & 15, to = t >> 4;
    const float* vb = qkv + ((size_t)b * QR + 128) * NSP + n0;
#pragma unroll
    for (int i = 0; i < 4; ++i) {
        int idx = t + 256 * i;
        int r = idx >> 4, q4 = idx & 15;
        float4 v = *reinterpret_cast<const float4*>(vb + (size_t)r * NSP + q4 * 4);
        *reinterpret_cast<float4*>(&vs[r][q4 * 4]) = v;
        float4 m = *reinterpret_cast<const float4*>(
            Mmat + ((size_t)b * 512 + o0 + r) * 64 + q4 * 4);
        msT[q4 * 4 + 0][r] = m.x; msT[q4 * 4 + 1][r] = m.y;
        msT[q4 * 4 + 2][r] = m.z; msT[q4 * 4 + 3][r] = m.w;
    }
    __syncthreads();
    float acc[4][4];
#pragma unroll
    for (int i = 0; i < 4; ++i)
#pragma unroll
        for (int j = 0; j < 4; ++j) acc[i][j] = 0.f;
#pragma unroll 8
    for (int kk = 0; kk < 64; ++kk) {
        float4 mv = *reinterpret_cast<const float4*>(&msT[kk][to * 4]);
        float4 vv = *reinterpret_cast<const float4*>(&vs[kk][tn * 4]);
        const float mr[4] = {mv.x, mv.y, mv.z, mv.w};
        const float vr[4] = {vv.x, vv.y, vv.z, vv.w};
#pragma unroll
        for (int i = 0; i < 4; ++i)
#pragma unroll
            for (int j = 0; j < 4; ++j)
                acc[i][j] = fmaf(mr[i], vr[j], acc[i][j]);
    }
#pragma unroll
    for (int i = 0; i < 4; ++i) {
        int o = o0 + to * 4 + i;
        float bias = bo[o];
        float4 ov;
        ov.x = acc[i][0] + bias; ov.y = acc[i][1] + bias;
        ov.z = acc[i][2] + bias; ov.w = acc[i][3] + bias;
        *reinterpret_cast<float4*>(
            out + ((size_t)b * 512 + o) * NSP + n0 + tn * 4) = ov;
    }
}

// ---------------------------------------------------------------------------
extern "C" void kernel_launch(void* const* d_in, const int* in_sizes, int n_in,
                              void* d_out, int out_size, void* d_ws, size_t ws_size,
                              hipStream_t stream)
{
    const float* x  = (const float*)d_in[0];
    const float* Wq = (const float*)d_in[1];
    const float* bq = (const float*)d_in[2];
    const float* Wk = (const float*)d_in[3];
    const float* bk = (const float*)d_in[4];
    const float* Wv = (const float*)d_in[5];
    const float* bv = (const float*)d_in[6];
    const float* Wo = (const float*)d_in[7];
    const float* bo = (const float*)d_in[8];
    float* out = (float*)d_out;

    float* ws   = (float*)d_ws;
    float* qkv  = ws;                                   // [B,192,N]    48 MiB
    float* part = qkv  + (size_t)B_SZ * QR * NSP;       // [B,32,64,64]  8 MiB
    float* attn = part + (size_t)B_SZ * 32 * 64 * 64;   // [B,64,64]   256 KiB
    float* Mmat = attn + (size_t)B_SZ * 64 * 64;        // [B,512,64]    2 MiB

    // whi/wlo overlap the `part` region: live only between k_convW and
    // k_qkv_mfma; k_energy overwrites part afterwards. Saves ws.
    unsigned short* whi = (unsigned short*)part;        // [192][512]  192 KiB
    unsigned short* wlo = whi + (size_t)QR * C_IN;      // [192][512]  192 KiB

    k_convW   <<<dim3(QR),          256, 0, stream>>>(Wq, Wk, Wv, whi, wlo);
    k_qkv_mfma<<<dim3(32, B_SZ),    512, 0, stream>>>(x, whi, wlo, bq, bk, bv, qkv);
    k_energy  <<<dim3(32, B_SZ),    256, 0, stream>>>(qkv, part);
    k_softmax <<<dim3(64, B_SZ),    256, 0, stream>>>(part, attn);
    k_woattn  <<<dim3(8, B_SZ),     256, 0, stream>>>(Wo, attn, Mmat);
    k_out     <<<dim3(64, 8, B_SZ), 256, 0, stream>>>(qkv, Mmat, bo, out);
}

// Round 3
// 308.589 us; speedup vs baseline: 1.5974x; 1.0810x over previous
//
#include <hip/hip_runtime.h>
#include <hip/hip_bf16.h>
#include <cstdint>

#define B_SZ 16
#define C_IN 512
#define C8   64
#define NSP  4096   // H*W
#define QR   192    // q,k,v stacked rows

typedef __attribute__((ext_vector_type(8))) short s8v;   // 8 bf16 (4 VGPRs)
typedef __attribute__((ext_vector_type(4))) float f4v;   // MFMA acc

// split fp32 -> truncated bf16 hi + bf16(residual). |x - hi - lo| <= ~2^-16 |x|
__device__ __forceinline__ void split_bf16(float x, unsigned short& h, unsigned short& l) {
    unsigned int u = __float_as_uint(x);
    h = (unsigned short)(u >> 16);
    float r = x - __uint_as_float(u & 0xffff0000u);
    l = (unsigned short)(__float_as_uint(r) >> 16);
}

__device__ __forceinline__ void split8(const float* v, s8v& h, s8v& l) {
#pragma unroll
    for (int j = 0; j < 8; ++j) {
        unsigned short hh, ll;
        split_bf16(v[j], hh, ll);
        h[j] = (short)hh; l[j] = (short)ll;
    }
}

// ---------------------------------------------------------------------------
// W pre-convert: stacked [192][512] -> whi/wlo bf16 (stored as ushort).
// ---------------------------------------------------------------------------
__global__ __launch_bounds__(256) void k_convW(
    const float* __restrict__ Wq, const float* __restrict__ Wk,
    const float* __restrict__ Wv,
    unsigned short* __restrict__ whi, unsigned short* __restrict__ wlo)
{
    const int o = blockIdx.x;
    const float* src = (o < 64)  ? (Wq + (size_t)o * C_IN)
                     : (o < 128) ? (Wk + (size_t)(o - 64) * C_IN)
                                 : (Wv + (size_t)(o - 128) * C_IN);
    for (int c = threadIdx.x; c < C_IN; c += 256) {
        unsigned short h, l;
        split_bf16(src[c], h, l);
        whi[(size_t)o * C_IN + c] = h;
        wlo[(size_t)o * C_IN + c] = l;
    }
}

// ---------------------------------------------------------------------------
// K1: qkv = W.x via split-bf16 MFMA (unchanged from round 2).
// ---------------------------------------------------------------------------
__global__ __launch_bounds__(512, 4) void k_qkv_mfma(
    const float* __restrict__ x,
    const unsigned short* __restrict__ whi, const unsigned short* __restrict__ wlo,
    const float* __restrict__ bq, const float* __restrict__ bk,
    const float* __restrict__ bv,
    float* __restrict__ qkv)
{
    __shared__ unsigned short as_h[QR * 32], as_l[QR * 32];
    __shared__ unsigned short xs_h[128 * 32], xs_l[128 * 32];

    const int b  = blockIdx.y;
    const int n0 = blockIdx.x * 128;
    const int t  = threadIdx.x;
    const int w  = t >> 6;
    const int l  = t & 63;
    const int wm = w >> 1;
    const int wn = w & 1;
    const int lm = l & 15;
    const int slot = (((l >> 4) ^ (l & 3)) << 3);

    const int nB    = t & 127;
    const int kgB   = t >> 7;
    const int slotB = ((kgB ^ (nB & 3)) << 3);

    f4v acc[3][4];
#pragma unroll
    for (int i = 0; i < 3; ++i)
#pragma unroll
        for (int j = 0; j < 4; ++j) acc[i][j] = (f4v)0.f;

    const float* xcol = x + ((size_t)b * C_IN) * NSP + n0 + nB;
    float xr[8];
    auto loadB = [&](int K0) {
        const float* s_ = xcol + (size_t)(K0 + kgB * 8) * NSP;
#pragma unroll
        for (int j = 0; j < 8; ++j) xr[j] = s_[(size_t)j * NSP];
    };
    loadB(0);

    for (int it = 0; it < 16; ++it) {
        const int k0 = it * 32;
        __syncthreads();
        {
            unsigned short h[8], lo[8];
#pragma unroll
            for (int j = 0; j < 8; ++j) split_bf16(xr[j], h[j], lo[j]);
            s8v hv, lv;
#pragma unroll
            for (int j = 0; j < 8; ++j) { hv[j] = (short)h[j]; lv[j] = (short)lo[j]; }
            *(s8v*)&xs_h[nB * 32 + slotB] = hv;
            *(s8v*)&xs_l[nB * 32 + slotB] = lv;
        }
        for (int c = t; c < 768; c += 512) {
            const int m = c >> 2, kga = c & 3;
            const int dst = m * 32 + ((kga ^ (m & 3)) << 3);
            const size_t srcoff = (size_t)m * C_IN + k0 + kga * 8;
            *(s8v*)&as_h[dst] = *(const s8v*)&whi[srcoff];
            *(s8v*)&as_l[dst] = *(const s8v*)&wlo[srcoff];
        }
        if (it < 15) loadB(k0 + 32);
        __syncthreads();
        s8v ah[3], al[3], bh[4], bl[4];
#pragma unroll
        for (int fm = 0; fm < 3; ++fm) {
            const int m = wm * 48 + fm * 16 + lm;
            ah[fm] = *(const s8v*)&as_h[m * 32 + slot];
            al[fm] = *(const s8v*)&as_l[m * 32 + slot];
        }
#pragma unroll
        for (int fn = 0; fn < 4; ++fn) {
            const int n = wn * 64 + fn * 16 + lm;
            bh[fn] = *(const s8v*)&xs_h[n * 32 + slot];
            bl[fn] = *(const s8v*)&xs_l[n * 32 + slot];
        }
#pragma unroll
        for (int fm = 0; fm < 3; ++fm)
#pragma unroll
            for (int fn = 0; fn < 4; ++fn) {
                acc[fm][fn] = __builtin_amdgcn_mfma_f32_16x16x32_bf16(
                    ah[fm], bh[fn], acc[fm][fn], 0, 0, 0);
                acc[fm][fn] = __builtin_amdgcn_mfma_f32_16x16x32_bf16(
                    ah[fm], bl[fn], acc[fm][fn], 0, 0, 0);
                acc[fm][fn] = __builtin_amdgcn_mfma_f32_16x16x32_bf16(
                    al[fm], bh[fn], acc[fm][fn], 0, 0, 0);
            }
    }

#pragma unroll
    for (int fm = 0; fm < 3; ++fm) {
        const int row0 = wm * 48 + fm * 16;
        const float* barr = (row0 < 64) ? bq : (row0 < 128) ? bk : bv;
        const int rbase = (row0 & 63) + (l >> 4) * 4;
        const int rowg  = row0 + (l >> 4) * 4;
#pragma unroll
        for (int fn = 0; fn < 4; ++fn) {
            const int col = n0 + wn * 64 + fn * 16 + lm;
            float* dst = qkv + ((size_t)b * QR + rowg) * NSP + col;
#pragma unroll
            for (int r = 0; r < 4; ++r)
                dst[(size_t)r * NSP] = acc[fm][fn][r] + barr[rbase + r];
        }
    }
}

// ---------------------------------------------------------------------------
// K2a: partial energy via split-bf16 MFMA, NO LDS. grid (32, B), 256 thr.
// Block handles n-chunk of 128 (4 k-steps of 32). Both q and k fragments are
// n-contiguous in global memory -> direct b128 loads + in-register split.
// part layout identical to round 2 ([b][32][64][64]) so k_softmax unchanged.
// ---------------------------------------------------------------------------
__global__ __launch_bounds__(256) void k_energy_mfma(
    const float* __restrict__ qkv, float* __restrict__ part)
{
    const int b = blockIdx.y, s = blockIdx.x;
    const int t = threadIdx.x, w = t >> 6, l = t & 63;
    const int lm = l & 15, lq = l >> 4;
    const float* qb = qkv + (size_t)b * QR * NSP + (size_t)s * 128;
    const float* kb = qb + (size_t)C8 * NSP;

    f4v acc[4];
#pragma unroll
    for (int fd = 0; fd < 4; ++fd) acc[fd] = (f4v)0.f;

#pragma unroll
    for (int ks = 0; ks < 4; ++ks) {
        // A frag: q[w*16+lm][ks*32 + lq*8 + j]
        const float* qrow = qb + (size_t)(w * 16 + lm) * NSP + ks * 32 + lq * 8;
        float qv[8];
        *(float4*)&qv[0] = *(const float4*)qrow;
        *(float4*)&qv[4] = *(const float4*)(qrow + 4);
        s8v qh, ql_;
        split8(qv, qh, ql_);
#pragma unroll
        for (int fd = 0; fd < 4; ++fd) {
            // B frag: k[fd*16+lm][ks*32 + lq*8 + j]
            const float* krow = kb + (size_t)(fd * 16 + lm) * NSP + ks * 32 + lq * 8;
            float kv[8];
            *(float4*)&kv[0] = *(const float4*)krow;
            *(float4*)&kv[4] = *(const float4*)(krow + 4);
            s8v kh, kl_;
            split8(kv, kh, kl_);
            acc[fd] = __builtin_amdgcn_mfma_f32_16x16x32_bf16(qh, kh,  acc[fd], 0, 0, 0);
            acc[fd] = __builtin_amdgcn_mfma_f32_16x16x32_bf16(qh, kl_, acc[fd], 0, 0, 0);
            acc[fd] = __builtin_amdgcn_mfma_f32_16x16x32_bf16(ql_, kh, acc[fd], 0, 0, 0);
        }
    }
    // C frag: c-row = w*16 + lq*4 + r, d-col = fd*16 + lm
    float* pb = part + ((size_t)b * 32 + s) * 4096;
#pragma unroll
    for (int fd = 0; fd < 4; ++fd)
#pragma unroll
        for (int r = 0; r < 4; ++r)
            pb[(w * 16 + lq * 4 + r) * 64 + fd * 16 + lm] = acc[fd][r];
}

// ---------------------------------------------------------------------------
// K2b: reduce partials + rowwise softmax (unchanged). grid (64, B).
// ---------------------------------------------------------------------------
__global__ __launch_bounds__(256) void k_softmax(
    const float* __restrict__ part, float* __restrict__ attn)
{
    __shared__ float red[4][64];
    const int cRow = blockIdx.x, b = blockIdx.y;
    const int t = threadIdx.x, d = t & 63, sg = t >> 6;
    const float* p = part + (size_t)b * 32 * 4096 + cRow * 64 + d;
    float s = 0.f;
#pragma unroll
    for (int i = 0; i < 8; ++i) s += p[(size_t)(sg * 8 + i) * 4096];
    red[sg][d] = s;
    __syncthreads();
    if (t < 64) {
        float v = red[0][d] + red[1][d] + red[2][d] + red[3][d];
        float m = v;
#pragma unroll
        for (int off = 32; off; off >>= 1) m = fmaxf(m, __shfl_xor(m, off));
        float e = __expf(v - m);
        float sum = e;
#pragma unroll
        for (int off = 32; off; off >>= 1) sum += __shfl_xor(sum, off);
        attn[((size_t)b * 64 + cRow) * 64 + d] = e / sum;
    }
}

// ---------------------------------------------------------------------------
// K2c: M = Wo @ attn (unchanged)
// ---------------------------------------------------------------------------
__global__ __launch_bounds__(256) void k_woattn(
    const float* __restrict__ Wo, const float* __restrict__ attn,
    float* __restrict__ Mmat)
{
    __shared__ float wosT[64][68];
    __shared__ float as[64][68];
    const int b  = blockIdx.y;
    const int o0 = blockIdx.x * 64;
    const int t  = threadIdx.x;
    const int td = t & 15, to = t >> 4;
#pragma unroll
    for (int i = 0; i < 4; ++i) {
        int idx = t + 256 * i;
        int r = idx >> 4, q4 = idx & 15;
        float4 w = *reinterpret_cast<const float4*>(
            Wo + (size_t)(o0 + r) * 64 + q4 * 4);
        wosT[q4 * 4 + 0][r] = w.x; wosT[q4 * 4 + 1][r] = w.y;
        wosT[q4 * 4 + 2][r] = w.z; wosT[q4 * 4 + 3][r] = w.w;
        float4 a = *reinterpret_cast<const float4*>(
            attn + ((size_t)b * 64 + r) * 64 + q4 * 4);
        *reinterpret_cast<float4*>(&as[r][q4 * 4]) = a;
    }
    __syncthreads();
    float acc[4][4];
#pragma unroll
    for (int i = 0; i < 4; ++i)
#pragma unroll
        for (int j = 0; j < 4; ++j) acc[i][j] = 0.f;
#pragma unroll 8
    for (int kk = 0; kk < 64; ++kk) {
        float4 wv = *reinterpret_cast<const float4*>(&wosT[kk][to * 4]);
        float4 av = *reinterpret_cast<const float4*>(&as[kk][td * 4]);
        const float wr[4] = {wv.x, wv.y, wv.z, wv.w};
        const float ar[4] = {av.x, av.y, av.z, av.w};
#pragma unroll
        for (int i = 0; i < 4; ++i)
#pragma unroll
            for (int j = 0; j < 4; ++j)
                acc[i][j] = fmaf(wr[i], ar[j], acc[i][j]);
    }
#pragma unroll
    for (int i = 0; i < 4; ++i) {
        float4 ov;
        ov.x = acc[i][0]; ov.y = acc[i][1]; ov.z = acc[i][2]; ov.w = acc[i][3];
        *reinterpret_cast<float4*>(
            Mmat + ((size_t)b * 512 + o0 + to * 4 + i) * 64 + td * 4) = ov;
    }
}

// ---------------------------------------------------------------------------
// K3: out = M @ v + bo via split-bf16 MFMA. grid (32, 8, B), 256 thr (4 waves).
// Block tile 64(o) x 128(n), K=64. v tile read fp32 coalesced, split in-reg,
// stored TRANSPOSED in LDS vsT[n][d] (ushort hi/lo) with XOR slot swizzle.
// M fragments loaded directly from global (L2-hot), split in-register.
// ---------------------------------------------------------------------------
__global__ __launch_bounds__(256) void k_out_mfma(
    const float* __restrict__ qkv, const float* __restrict__ Mmat,
    const float* __restrict__ bo, float* __restrict__ out)
{
    __shared__ unsigned short vsT_h[128 * 64];   // [n][d], swizzled
    __shared__ unsigned short vsT_l[128 * 64];
    const int b  = blockIdx.z;
    const int o0 = blockIdx.y * 64;
    const int n0 = blockIdx.x * 128;
    const int t  = threadIdx.x;
    const int w  = t >> 6, l = t & 63;
    const int lm = l & 15, lq = l >> 4;

    const float* vb = qkv + ((size_t)b * QR + 128) * NSP;  // v: [64][NSP]

    // ---- stage v^T: element (n, d) -> byte n*128 + ((d>>3)^(n&7))*16 + (d&7)*2
#pragma unroll
    for (int s = 0; s < 2; ++s)
#pragma unroll
        for (int dd = 0; dd < 16; ++dd) {
            const int d = w + 4 * dd;        // wave w covers d = w, w+4, ...
            const int n = 64 * s + l;        // lanes: consecutive n (coalesced)
            float xv = vb[(size_t)d * NSP + n0 + n];
            unsigned short h, lo_;
            split_bf16(xv, h, lo_);
            const int addr = n * 64 + ((((d >> 3) ^ (n & 7))) << 3) + (d & 7);
            vsT_h[addr] = h;
            vsT_l[addr] = lo_;
        }

    // ---- A fragments: M[o0 + fo*16 + lm][ks*32 + lq*8 + j], global, split
    s8v ah[4][2], al[4][2];
#pragma unroll
    for (int fo = 0; fo < 4; ++fo)
#pragma unroll
        for (int ks = 0; ks < 2; ++ks) {
            const float* mrow = Mmat + ((size_t)b * 512 + o0 + fo * 16 + lm) * 64
                                + ks * 32 + lq * 8;
            float mv[8];
            *(float4*)&mv[0] = *(const float4*)mrow;
            *(float4*)&mv[4] = *(const float4*)(mrow + 4);
            split8(mv, ah[fo][ks], al[fo][ks]);
        }
    __syncthreads();

    f4v acc[4][2];
#pragma unroll
    for (int fo = 0; fo < 4; ++fo)
#pragma unroll
        for (int fn = 0; fn < 2; ++fn) acc[fo][fn] = (f4v)0.f;

    const int nwbase = w * 32;   // wave n-range
#pragma unroll
    for (int ks = 0; ks < 2; ++ks) {
        s8v bh[2], bl[2];
#pragma unroll
        for (int fn = 0; fn < 2; ++fn) {
            const int n = nwbase + fn * 16 + lm;
            const int slot = (ks * 4 + lq) ^ (n & 7);
            const int addr = n * 64 + (slot << 3);
            bh[fn] = *(const s8v*)&vsT_h[addr];
            bl[fn] = *(const s8v*)&vsT_l[addr];
        }
#pragma unroll
        for (int fo = 0; fo < 4; ++fo)
#pragma unroll
            for (int fn = 0; fn < 2; ++fn) {
                acc[fo][fn] = __builtin_amdgcn_mfma_f32_16x16x32_bf16(
                    ah[fo][ks], bh[fn], acc[fo][fn], 0, 0, 0);
                acc[fo][fn] = __builtin_amdgcn_mfma_f32_16x16x32_bf16(
                    ah[fo][ks], bl[fn], acc[fo][fn], 0, 0, 0);
                acc[fo][fn] = __builtin_amdgcn_mfma_f32_16x16x32_bf16(
                    al[fo][ks], bh[fn], acc[fo][fn], 0, 0, 0);
            }
    }

    // ---- epilogue: bias + store
#pragma unroll
    for (int fo = 0; fo < 4; ++fo) {
        const int orow0 = o0 + fo * 16 + lq * 4;
#pragma unroll
        for (int fn = 0; fn < 2; ++fn) {
            const int col = n0 + nwbase + fn * 16 + lm;
            float* dst = out + ((size_t)b * 512 + orow0) * NSP + col;
#pragma unroll
            for (int r = 0; r < 4; ++r)
                dst[(size_t)r * NSP] = acc[fo][fn][r] + bo[orow0 + r];
        }
    }
}

// ---------------------------------------------------------------------------
extern "C" void kernel_launch(void* const* d_in, const int* in_sizes, int n_in,
                              void* d_out, int out_size, void* d_ws, size_t ws_size,
                              hipStream_t stream)
{
    const float* x  = (const float*)d_in[0];
    const float* Wq = (const float*)d_in[1];
    const float* bq = (const float*)d_in[2];
    const float* Wk = (const float*)d_in[3];
    const float* bk = (const float*)d_in[4];
    const float* Wv = (const float*)d_in[5];
    const float* bv = (const float*)d_in[6];
    const float* Wo = (const float*)d_in[7];
    const float* bo = (const float*)d_in[8];
    float* out = (float*)d_out;

    float* ws   = (float*)d_ws;
    float* qkv  = ws;                                   // [B,192,N]    48 MiB
    float* part = qkv  + (size_t)B_SZ * QR * NSP;       // [B,32,64,64]  8 MiB
    float* attn = part + (size_t)B_SZ * 32 * 64 * 64;   // [B,64,64]   256 KiB
    float* Mmat = attn + (size_t)B_SZ * 64 * 64;        // [B,512,64]    2 MiB

    // whi/wlo overlap `part`: live only until k_qkv_mfma; k_energy_mfma
    // overwrites part afterwards.
    unsigned short* whi = (unsigned short*)part;        // [192][512]  192 KiB
    unsigned short* wlo = whi + (size_t)QR * C_IN;      // [192][512]  192 KiB

    k_convW      <<<dim3(QR),          256, 0, stream>>>(Wq, Wk, Wv, whi, wlo);
    k_qkv_mfma   <<<dim3(32, B_SZ),    512, 0, stream>>>(x, whi, wlo, bq, bk, bv, qkv);
    k_energy_mfma<<<dim3(32, B_SZ),    256, 0, stream>>>(qkv, part);
    k_softmax    <<<dim3(64, B_SZ),    256, 0, stream>>>(part, attn);
    k_woattn     <<<dim3(8, B_SZ),     256, 0, stream>>>(Wo, attn, Mmat);
    k_out_mfma   <<<dim3(32, 8, B_SZ), 256, 0, stream>>>(qkv, Mmat, bo, out);
}

// Round 6
// 293.667 us; speedup vs baseline: 1.6786x; 1.0508x over previous
//
#include <hip/hip_runtime.h>
#include <hip/hip_bf16.h>
#include <cstdint>

#define B_SZ 16
#define C_IN 512
#define C8   64
#define NSP  4096   // H*W
#define QR   192    // q,k,v stacked rows

typedef __attribute__((ext_vector_type(8))) short s8v;   // 8 bf16 (4 VGPRs)
typedef __attribute__((ext_vector_type(4))) float f4v;   // MFMA acc

// split fp32 -> truncated bf16 hi + bf16(residual). |x - hi - lo| <= ~2^-16 |x|
__device__ __forceinline__ void split_bf16(float x, unsigned short& h, unsigned short& l) {
    unsigned int u = __float_as_uint(x);
    h = (unsigned short)(u >> 16);
    float r = x - __uint_as_float(u & 0xffff0000u);
    l = (unsigned short)(__float_as_uint(r) >> 16);
}

__device__ __forceinline__ void split8(const float* v, s8v& h, s8v& l) {
#pragma unroll
    for (int j = 0; j < 8; ++j) {
        unsigned short hh, ll;
        split_bf16(v[j], hh, ll);
        h[j] = (short)hh; l[j] = (short)ll;
    }
}

// swizzled address into the fp32 [128][128] epilogue LDS (floats).
// slot = 4 floats; XOR bits 2..4 of slot with row&7. 8-float frag reads stay
// two contiguous float4s (mask has no bit0; base slot is even).
__device__ __forceinline__ int eqaddr(int row, int n) {
    return row * 128 + ((((n >> 2) ^ ((row & 7) << 2)) << 2) | (n & 3));
}

// ---------------------------------------------------------------------------
// W pre-convert: stacked [192][512] -> whi/wlo bf16 (stored as ushort).
// ---------------------------------------------------------------------------
__global__ __launch_bounds__(256) void k_convW(
    const float* __restrict__ Wq, const float* __restrict__ Wk,
    const float* __restrict__ Wv,
    unsigned short* __restrict__ whi, unsigned short* __restrict__ wlo)
{
    const int o = blockIdx.x;
    const float* src = (o < 64)  ? (Wq + (size_t)o * C_IN)
                     : (o < 128) ? (Wk + (size_t)(o - 64) * C_IN)
                                 : (Wv + (size_t)(o - 128) * C_IN);
    for (int c = threadIdx.x; c < C_IN; c += 256) {
        unsigned short h, l;
        split_bf16(src[c], h, l);
        whi[(size_t)o * C_IN + c] = h;
        wlo[(size_t)o * C_IN + c] = l;
    }
}

// ---------------------------------------------------------------------------
// K1: fused QKV projection + partial energy.
// grid (32, B), 512 thr = 8 waves (4M x 2N). Block tile 192x128, BK=32.
// Main loop: split-bf16 MFMA (as round 2/3, verified). Epilogue: v rows ->
// global; q,k rows (bias-added) -> swizzled fp32 LDS (64KB union with staging
// buffers); QK^T over K=128 via split MFMA; part[b][s][64][64] stored.
// ---------------------------------------------------------------------------
__global__ __launch_bounds__(512, 4) void k_qkv_en(
    const float* __restrict__ x,
    const unsigned short* __restrict__ whi, const unsigned short* __restrict__ wlo,
    const float* __restrict__ bq, const float* __restrict__ bk,
    const float* __restrict__ bv,
    float* __restrict__ v, float* __restrict__ part)
{
    __shared__ __align__(16) unsigned char smem[65536];
    unsigned short* as_h = (unsigned short*)smem;          // [QR*32]
    unsigned short* as_l = as_h + QR * 32;
    unsigned short* xs_h = as_l + QR * 32;                 // [128*32]
    unsigned short* xs_l = xs_h + 128 * 32;
    float* eq = (float*)smem;                              // [128*128] (epilogue)

    const int b  = blockIdx.y;
    const int s  = blockIdx.x;
    const int n0 = s * 128;
    const int t  = threadIdx.x;
    const int w  = t >> 6, l = t & 63;
    const int wm = w >> 1, wn = w & 1;
    const int lm = l & 15, lq = l >> 4;
    const int slot = ((lq ^ (l & 3)) << 3);

    const int nB = t & 127, kgB = t >> 7;
    const int slotB = ((kgB ^ (nB & 3)) << 3);

    const int mW = t >> 2, kgW = t & 3;                    // W staging item 0
    const int dstW0 = mW * 32 + ((kgW ^ (mW & 3)) << 3);   // item 1: +4096
    const size_t sW0 = (size_t)mW * C_IN + kgW * 8;        // item 1: +65536

    f4v acc[3][4];
#pragma unroll
    for (int i = 0; i < 3; ++i)
#pragma unroll
        for (int j = 0; j < 4; ++j) acc[i][j] = (f4v)0.f;

    const float* xcol = x + (size_t)b * C_IN * NSP + n0 + nB;
    float xr[8];
    auto loadB = [&](int K0) {
        const float* s_ = xcol + (size_t)(K0 + kgB * 8) * NSP;
#pragma unroll
        for (int j = 0; j < 8; ++j) xr[j] = s_[(size_t)j * NSP];
    };
    loadB(0);

    for (int it = 0; it < 16; ++it) {
        const int k0 = it * 32;
        __syncthreads();
        // split current x chunk (regs) BEFORE prefetch clobbers xr
        s8v hv, lv;
        {
            unsigned short h, lo_;
#pragma unroll
            for (int j = 0; j < 8; ++j) {
                split_bf16(xr[j], h, lo_);
                hv[j] = (short)h; lv[j] = (short)lo_;
            }
        }
        if (it < 15) loadB(k0 + 32);         // next x: latency spans compute
        // W loads -> regs first (latency hides under the LDS writes below)
        s8v wh0 = *(const s8v*)&whi[sW0 + k0];
        s8v wl0 = *(const s8v*)&wlo[sW0 + k0];
        s8v wh1, wl1;
        if (t < 256) {
            wh1 = *(const s8v*)&whi[sW0 + 65536 + k0];
            wl1 = *(const s8v*)&wlo[sW0 + 65536 + k0];
        }
        *(s8v*)&xs_h[nB * 32 + slotB] = hv;
        *(s8v*)&xs_l[nB * 32 + slotB] = lv;
        *(s8v*)&as_h[dstW0] = wh0;
        *(s8v*)&as_l[dstW0] = wl0;
        if (t < 256) {
            *(s8v*)&as_h[dstW0 + 4096] = wh1;
            *(s8v*)&as_l[dstW0 + 4096] = wl1;
        }
        __syncthreads();
        s8v ah[3], al[3], bh[4], bl[4];
#pragma unroll
        for (int fm = 0; fm < 3; ++fm) {
            const int m = wm * 48 + fm * 16 + lm;
            ah[fm] = *(const s8v*)&as_h[m * 32 + slot];
            al[fm] = *(const s8v*)&as_l[m * 32 + slot];
        }
#pragma unroll
        for (int fn = 0; fn < 4; ++fn) {
            const int n = wn * 64 + fn * 16 + lm;
            bh[fn] = *(const s8v*)&xs_h[n * 32 + slot];
            bl[fn] = *(const s8v*)&xs_l[n * 32 + slot];
        }
#pragma unroll
        for (int fm = 0; fm < 3; ++fm)
#pragma unroll
            for (int fn = 0; fn < 4; ++fn) {
                acc[fm][fn] = __builtin_amdgcn_mfma_f32_16x16x32_bf16(
                    ah[fm], bh[fn], acc[fm][fn], 0, 0, 0);
                acc[fm][fn] = __builtin_amdgcn_mfma_f32_16x16x32_bf16(
                    ah[fm], bl[fn], acc[fm][fn], 0, 0, 0);
                acc[fm][fn] = __builtin_amdgcn_mfma_f32_16x16x32_bf16(
                    al[fm], bh[fn], acc[fm][fn], 0, 0, 0);
            }
    }

    // ================= epilogue =================
    __syncthreads();   // all frag reads of staging LDS done; repurpose as eq
    // v rows -> global; q,k rows (bias-added) -> eq LDS
#pragma unroll
    for (int fm = 0; fm < 3; ++fm) {
        const int row0f = wm * 48 + fm * 16;   // 16-row segment, class-uniform
        const int rbase = row0f + lq * 4;
        if (row0f >= 128) {
#pragma unroll
            for (int fn = 0; fn < 4; ++fn) {
                const int n = wn * 64 + fn * 16 + lm;
                float* dst = v + ((size_t)b * 64 + (rbase - 128)) * NSP + n0 + n;
#pragma unroll
                for (int r = 0; r < 4; ++r)
                    dst[(size_t)r * NSP] = acc[fm][fn][r] + bv[rbase - 128 + r];
            }
        } else {
            const float* barr = (row0f < 64) ? bq : bk;
            const int boff = rbase & 63;
#pragma unroll
            for (int fn = 0; fn < 4; ++fn) {
                const int n = wn * 64 + fn * 16 + lm;
#pragma unroll
                for (int r = 0; r < 4; ++r)
                    eq[eqaddr(rbase + r, n)] = acc[fm][fn][r] + barr[boff + r];
            }
        }
    }
    __syncthreads();

    // QK^T: 16 output tiles (4 fc x 4 fd); wave w -> fc = w>>1, fd = (w&1)*2+{0,1}
    const int fc = w >> 1, fd0 = (w & 1) * 2;
    f4v e0 = (f4v)0.f, e1 = (f4v)0.f;
#pragma unroll
    for (int ks = 0; ks < 4; ++ks) {
        const int nf = ks * 32 + lq * 8;
        float qa[8];
        {
            const int a0 = eqaddr(fc * 16 + lm, nf);
            *(float4*)&qa[0] = *(const float4*)&eq[a0];
            *(float4*)&qa[4] = *(const float4*)&eq[a0 + 4];
        }
        s8v qh, ql_;
        split8(qa, qh, ql_);
        float ka[8];
        {
            const int a0 = eqaddr(64 + fd0 * 16 + lm, nf);
            *(float4*)&ka[0] = *(const float4*)&eq[a0];
            *(float4*)&ka[4] = *(const float4*)&eq[a0 + 4];
        }
        s8v kh, kl_;
        split8(ka, kh, kl_);
        e0 = __builtin_amdgcn_mfma_f32_16x16x32_bf16(qh, kh,  e0, 0, 0, 0);
        e0 = __builtin_amdgcn_mfma_f32_16x16x32_bf16(qh, kl_, e0, 0, 0, 0);
        e0 = __builtin_amdgcn_mfma_f32_16x16x32_bf16(ql_, kh, e0, 0, 0, 0);
        {
            const int a0 = eqaddr(64 + (fd0 + 1) * 16 + lm, nf);
            *(float4*)&ka[0] = *(const float4*)&eq[a0];
            *(float4*)&ka[4] = *(const float4*)&eq[a0 + 4];
        }
        split8(ka, kh, kl_);
        e1 = __builtin_amdgcn_mfma_f32_16x16x32_bf16(qh, kh,  e1, 0, 0, 0);
        e1 = __builtin_amdgcn_mfma_f32_16x16x32_bf16(qh, kl_, e1, 0, 0, 0);
        e1 = __builtin_amdgcn_mfma_f32_16x16x32_bf16(ql_, kh, e1, 0, 0, 0);
    }
    float* pb = part + ((size_t)b * 32 + s) * 4096;
#pragma unroll
    for (int r = 0; r < 4; ++r) {
        const int c = fc * 16 + lq * 4 + r;
        pb[c * 64 + fd0 * 16 + lm]        = e0[r];
        pb[c * 64 + (fd0 + 1) * 16 + lm]  = e1[r];
    }
}

// ---------------------------------------------------------------------------
// K2b: reduce partials + rowwise softmax (unchanged). grid (64, B).
// ---------------------------------------------------------------------------
__global__ __launch_bounds__(256) void k_softmax(
    const float* __restrict__ part, float* __restrict__ attn)
{
    __shared__ float red[4][64];
    const int cRow = blockIdx.x, b = blockIdx.y;
    const int t = threadIdx.x, d = t & 63, sg = t >> 6;
    const float* p = part + (size_t)b * 32 * 4096 + cRow * 64 + d;
    float s = 0.f;
#pragma unroll
    for (int i = 0; i < 8; ++i) s += p[(size_t)(sg * 8 + i) * 4096];
    red[sg][d] = s;
    __syncthreads();
    if (t < 64) {
        float v = red[0][d] + red[1][d] + red[2][d] + red[3][d];
        float m = v;
#pragma unroll
        for (int off = 32; off; off >>= 1) m = fmaxf(m, __shfl_xor(m, off));
        float e = __expf(v - m);
        float sum = e;
#pragma unroll
        for (int off = 32; off; off >>= 1) sum += __shfl_xor(sum, off);
        attn[((size_t)b * 64 + cRow) * 64 + d] = e / sum;
    }
}

// ---------------------------------------------------------------------------
// K2c: M = Wo @ attn, stored pre-split as bf16 hi/lo. grid (8, B).
// ---------------------------------------------------------------------------
__global__ __launch_bounds__(256) void k_woattn(
    const float* __restrict__ Wo, const float* __restrict__ attn,
    unsigned short* __restrict__ mhi, unsigned short* __restrict__ mlo)
{
    __shared__ float wosT[64][68];
    __shared__ float as[64][68];
    const int b  = blockIdx.y;
    const int o0 = blockIdx.x * 64;
    const int t  = threadIdx.x;
    const int td = t & 15, to = t >> 4;
#pragma unroll
    for (int i = 0; i < 4; ++i) {
        int idx = t + 256 * i;
        int r = idx >> 4, q4 = idx & 15;
        float4 w = *reinterpret_cast<const float4*>(
            Wo + (size_t)(o0 + r) * 64 + q4 * 4);
        wosT[q4 * 4 + 0][r] = w.x; wosT[q4 * 4 + 1][r] = w.y;
        wosT[q4 * 4 + 2][r] = w.z; wosT[q4 * 4 + 3][r] = w.w;
        float4 a = *reinterpret_cast<const float4*>(
            attn + ((size_t)b * 64 + r) * 64 + q4 * 4);
        *reinterpret_cast<float4*>(&as[r][q4 * 4]) = a;
    }
    __syncthreads();
    float acc[4][4];
#pragma unroll
    for (int i = 0; i < 4; ++i)
#pragma unroll
        for (int j = 0; j < 4; ++j) acc[i][j] = 0.f;
#pragma unroll 8
    for (int kk = 0; kk < 64; ++kk) {
        float4 wv = *reinterpret_cast<const float4*>(&wosT[kk][to * 4]);
        float4 av = *reinterpret_cast<const float4*>(&as[kk][td * 4]);
        const float wr[4] = {wv.x, wv.y, wv.z, wv.w};
        const float ar[4] = {av.x, av.y, av.z, av.w};
#pragma unroll
        for (int i = 0; i < 4; ++i)
#pragma unroll
            for (int j = 0; j < 4; ++j)
                acc[i][j] = fmaf(wr[i], ar[j], acc[i][j]);
    }
#pragma unroll
    for (int i = 0; i < 4; ++i) {
        unsigned short h[4], lo4[4];
#pragma unroll
        for (int j = 0; j < 4; ++j) split_bf16(acc[i][j], h[j], lo4[j]);
        const size_t base = ((size_t)b * 512 + o0 + to * 4 + i) * 64 + td * 4;
        uint2 hp, lp;
        hp.x = (unsigned)h[0]   | ((unsigned)h[1]   << 16);
        hp.y = (unsigned)h[2]   | ((unsigned)h[3]   << 16);
        lp.x = (unsigned)lo4[0] | ((unsigned)lo4[1] << 16);
        lp.y = (unsigned)lo4[2] | ((unsigned)lo4[3] << 16);
        *reinterpret_cast<uint2*>(&mhi[base]) = hp;
        *reinterpret_cast<uint2*>(&mlo[base]) = lp;
    }
}

// ---------------------------------------------------------------------------
// K3: out = M @ v + bo. grid (64, B), 512 thr = 8 waves; block = all 512 o
// x 64 n, so the v tile is read from HBM exactly once. M pre-split (L2-hot).
// ---------------------------------------------------------------------------
__global__ __launch_bounds__(512, 2) void k_out2(
    const float* __restrict__ v,
    const unsigned short* __restrict__ mhi, const unsigned short* __restrict__ mlo,
    const float* __restrict__ bo, float* __restrict__ out)
{
    __shared__ unsigned short vsT_h[64 * 64];   // [n][d], swizzled
    __shared__ unsigned short vsT_l[64 * 64];
    const int b  = blockIdx.y;
    const int n0 = blockIdx.x * 64;
    const int t  = threadIdx.x;
    const int w  = t >> 6, l = t & 63;
    const int lm = l & 15, lq = l >> 4;

    // stage v^T: wave w loads d-rows w*8..w*8+7, lane = n (coalesced 256B)
#pragma unroll
    for (int i = 0; i < 8; ++i) {
        const int d = w * 8 + i;
        const float xv = v[((size_t)b * 64 + d) * NSP + n0 + l];
        unsigned short h, lo_;
        split_bf16(xv, h, lo_);
        const int addr = l * 64 + ((((d >> 3) ^ (l & 7))) << 3) + (d & 7);
        vsT_h[addr] = h;
        vsT_l[addr] = lo_;
    }
    __syncthreads();

    f4v acc[4][4];
#pragma unroll
    for (int i = 0; i < 4; ++i)
#pragma unroll
        for (int j = 0; j < 4; ++j) acc[i][j] = (f4v)0.f;

    const int obase = w * 64;
#pragma unroll
    for (int ks = 0; ks < 2; ++ks) {
        s8v bh[4], bl[4];
#pragma unroll
        for (int fn = 0; fn < 4; ++fn) {
            const int n = fn * 16 + lm;
            const int addr = n * 64 + ((((ks * 4 + lq) ^ (n & 7))) << 3);
            bh[fn] = *(const s8v*)&vsT_h[addr];
            bl[fn] = *(const s8v*)&vsT_l[addr];
        }
#pragma unroll
        for (int fo = 0; fo < 4; ++fo) {
            const int o = obase + fo * 16 + lm;
            const size_t moff = ((size_t)b * 512 + o) * 64 + ks * 32 + lq * 8;
            s8v ah  = *(const s8v*)&mhi[moff];
            s8v al_ = *(const s8v*)&mlo[moff];
#pragma unroll
            for (int fn = 0; fn < 4; ++fn) {
                acc[fo][fn] = __builtin_amdgcn_mfma_f32_16x16x32_bf16(
                    ah, bh[fn], acc[fo][fn], 0, 0, 0);
                acc[fo][fn] = __builtin_amdgcn_mfma_f32_16x16x32_bf16(
                    ah, bl[fn], acc[fo][fn], 0, 0, 0);
                acc[fo][fn] = __builtin_amdgcn_mfma_f32_16x16x32_bf16(
                    al_, bh[fn], acc[fo][fn], 0, 0, 0);
            }
        }
    }

#pragma unroll
    for (int fo = 0; fo < 4; ++fo) {
        const int orow = obase + fo * 16 + lq * 4;
#pragma unroll
        for (int fn = 0; fn < 4; ++fn) {
            const int nc = n0 + fn * 16 + lm;
            float* dst = out + ((size_t)b * 512 + orow) * NSP + nc;
#pragma unroll
            for (int r = 0; r < 4; ++r)
                dst[(size_t)r * NSP] = acc[fo][fn][r] + bo[orow + r];
        }
    }
}

// ---------------------------------------------------------------------------
extern "C" void kernel_launch(void* const* d_in, const int* in_sizes, int n_in,
                              void* d_out, int out_size, void* d_ws, size_t ws_size,
                              hipStream_t stream)
{
    const float* x  = (const float*)d_in[0];
    const float* Wq = (const float*)d_in[1];
    const float* bq = (const float*)d_in[2];
    const float* Wk = (const float*)d_in[3];
    const float* bk = (const float*)d_in[4];
    const float* Wv = (const float*)d_in[5];
    const float* bv = (const float*)d_in[6];
    const float* Wo = (const float*)d_in[7];
    const float* bo = (const float*)d_in[8];
    float* out = (float*)d_out;

    float* ws   = (float*)d_ws;
    float* v    = ws;                                    // [B,64,N]     16.8 MB
    float* part = v    + (size_t)B_SZ * 64 * NSP;        // [B,32,64,64]  8.4 MB
    float* attn = part + (size_t)B_SZ * 32 * 64 * 64;    // [B,64,64]   256 KiB
    unsigned short* mhi = (unsigned short*)(attn + (size_t)B_SZ * 64 * 64);
    unsigned short* mlo = mhi + (size_t)B_SZ * 512 * 64; // 1 MiB each
    unsigned short* whi = mlo + (size_t)B_SZ * 512 * 64; // [192][512] 192 KiB
    unsigned short* wlo = whi + (size_t)QR * C_IN;

    k_convW  <<<dim3(QR),      256, 0, stream>>>(Wq, Wk, Wv, whi, wlo);
    k_qkv_en <<<dim3(32, B_SZ), 512, 0, stream>>>(x, whi, wlo, bq, bk, bv, v, part);
    k_softmax<<<dim3(64, B_SZ), 256, 0, stream>>>(part, attn);
    k_woattn <<<dim3(8, B_SZ),  256, 0, stream>>>(Wo, attn, mhi, mlo);
    k_out2   <<<dim3(64, B_SZ), 512, 0, stream>>>(v, mhi, mlo, bo, out);
}